// Round 1
// baseline (348.004 us; speedup 1.0000x reference)
//
#include <hip/hip_runtime.h>

#define LV 32
#define NBINS (LV*LV)
#define IMG_H 512
#define IMG_W 512
#define NIMG 64
#define NOFF 8

// OFFSETS = [(round(sin(a)*d), round(cos(a)*d)) for d in (1,2) for a in (0,45,90,135)]
// -> (0,1),(1,1),(1,0),(1,-1),(0,2),(1,1),(2,0),(1,-1)
__device__ __constant__ int OFF_DR[NOFF] = {0, 1, 1, 1, 0, 1, 2, 1};
__device__ __constant__ int OFF_DC[NOFF] = {1, 1, 0, -1, 2, 1, 0, -1};

// ---------------- Kernel 1: quantize (HBM-bound) ----------------
__device__ __forceinline__ unsigned char quant1(float x, float y, float z) {
    float gray = (x + y + z) / 3.0f;              // match jnp.mean(axis=1)
    float t = (gray + 1.0f) * 0.5f * 31.0f;       // (g+1)*0.5*(L-1)
    t = fminf(fmaxf(t, 0.0f), 31.0f);             // clip
    return (unsigned char)(int)t;                 // astype(int32) truncates
}

__global__ __launch_bounds__(256) void quantize_kernel(
    const float* __restrict__ in, unsigned char* __restrict__ g, int n4) {
    const int stride = gridDim.x * blockDim.x;
    for (int q = blockIdx.x * blockDim.x + threadIdx.x; q < n4; q += stride) {
        int pix = q << 2;                         // 4 pixels per thread
        int b = pix >> 18;                        // / (512*512)
        int within = pix & (IMG_H * IMG_W - 1);
        const float* base = in + (size_t)b * (3 * IMG_H * IMG_W) + within;
        float4 c0 = *(const float4*)(base);
        float4 c1 = *(const float4*)(base + IMG_H * IMG_W);
        float4 c2 = *(const float4*)(base + 2 * IMG_H * IMG_W);
        uchar4 o;
        o.x = quant1(c0.x, c1.x, c2.x);
        o.y = quant1(c0.y, c1.y, c2.y);
        o.z = quant1(c0.z, c1.z, c2.z);
        o.w = quant1(c0.w, c1.w, c2.w);
        *(uchar4*)(g + pix) = o;
    }
}

// ---------------- Kernel 2: histogram + features ----------------
// one block per (image, offset); 256 threads, 4 per-wave sub-histograms.
__device__ __forceinline__ int hswz(int i, int j) {
    // bank = addr%32 = (i+j)&31 -> spreads the Gaussian-peaked j across banks
    return (i << 5) | ((i + j) & 31);
}

__global__ __launch_bounds__(256) void glcm_kernel(
    const unsigned char* __restrict__ g, float* __restrict__ feats) {
    const int blk = blockIdx.x;
    const int b = blk >> 3;
    const int o = blk & 7;
    const int dr = OFF_DR[o], dc = OFF_DC[o];
    const int r0 = dr < 0 ? -dr : 0;
    const int r1 = IMG_H - (dr > 0 ? dr : 0);
    const int c0 = dc < 0 ? -dc : 0;
    const int c1 = IMG_W - (dc > 0 ? dc : 0);

    __shared__ unsigned int hist[4][NBINS];       // 16 KB
    __shared__ unsigned int comb[NBINS];          // 4 KB
    __shared__ float red[4][6];

    const int tid = threadIdx.x;
    const int wid = tid >> 6;
    const int lane = tid & 63;

    for (int k = tid; k < 4 * NBINS; k += 256) ((unsigned int*)hist)[k] = 0;
    __syncthreads();

    const unsigned char* gb = g + (size_t)b * (IMG_H * IMG_W);
    for (int r = r0; r < r1; ++r) {
        const unsigned char* rowi = gb + r * IMG_W;
        const unsigned char* rowj = gb + (r + dr) * IMG_W + dc;
        for (int c = c0 + tid; c < c1; c += 256) {
            int i = rowi[c];
            int j = rowj[c];
            atomicAdd(&hist[wid][hswz(i, j)], 1u);
        }
    }
    __syncthreads();

    for (int k = tid; k < NBINS; k += 256) {
        int i = k >> 5, j = k & 31;
        int s = hswz(i, j);
        comb[k] = hist[0][s] + hist[1][s] + hist[2][s] + hist[3][s];
    }
    __syncthreads();

    const int npix = (r1 - r0) * (c1 - c0);
    const float inv_total = 1.0f / (2.0f * (float)npix);

    float c_sum = 0.f, h_sum = 0.f, e_sum = 0.f, m1 = 0.f, m2 = 0.f, m12 = 0.f;
    for (int k = tid; k < NBINS; k += 256) {
        int i = k >> 5, j = k & 31;
        float sym = (float)(comb[k] + comb[(j << 5) | i]);
        float P = sym * inv_total;
        float d = (float)(i - j);
        float d2 = d * d;
        float fi = (float)i, fj = (float)j;
        c_sum += P * d2;
        h_sum += P / (1.0f + d2);
        e_sum += P * P;
        m1  += P * fi;
        m2  += P * fi * fi;
        m12 += P * fi * fj;
    }

    // wave64 butterfly-down reduce
    #pragma unroll
    for (int s = 32; s > 0; s >>= 1) {
        c_sum += __shfl_down(c_sum, s);
        h_sum += __shfl_down(h_sum, s);
        e_sum += __shfl_down(e_sum, s);
        m1    += __shfl_down(m1, s);
        m2    += __shfl_down(m2, s);
        m12   += __shfl_down(m12, s);
    }
    if (lane == 0) {
        red[wid][0] = c_sum; red[wid][1] = h_sum; red[wid][2] = e_sum;
        red[wid][3] = m1;    red[wid][4] = m2;    red[wid][5] = m12;
    }
    __syncthreads();

    if (tid == 0) {
        float rc = 0, rh = 0, re = 0, rm1 = 0, rm2 = 0, rm12 = 0;
        #pragma unroll
        for (int w = 0; w < 4; ++w) {
            rc += red[w][0]; rh += red[w][1]; re += red[w][2];
            rm1 += red[w][3]; rm2 += red[w][4]; rm12 += red[w][5];
        }
        float mu  = rm1;
        float var = rm2 - mu * mu;
        float cov = rm12 - mu * mu;
        float denom = sqrtf(fmaxf(var, 0.f)) * sqrtf(fmaxf(var, 0.f));
        float corr = (denom > 1e-15f) ? cov / denom : 1.0f;
        float* f = feats + (size_t)(b * NOFF + o) * 4;
        f[0] = rc;
        f[1] = rh;
        f[2] = sqrtf(re);
        f[3] = corr;
    }
}

// ---------------- Kernel 3: average over offsets ----------------
__global__ __launch_bounds__(256) void reduce_kernel(
    const float* __restrict__ feats, float* __restrict__ out) {
    int tid = threadIdx.x;            // 256 = 4 features x 64 images
    int f = tid >> 6, b = tid & 63;
    float s = 0.f;
    #pragma unroll
    for (int o = 0; o < NOFF; ++o) s += feats[(size_t)(b * NOFF + o) * 4 + f];
    out[f * NIMG + b] = s * 0.125f;
}

extern "C" void kernel_launch(void* const* d_in, const int* in_sizes, int n_in,
                              void* d_out, int out_size, void* d_ws, size_t ws_size,
                              hipStream_t stream) {
    const float* images = (const float*)d_in[0];
    float* out = (float*)d_out;

    unsigned char* g = (unsigned char*)d_ws;                         // 16 MB
    float* feats = (float*)((char*)d_ws + (size_t)NIMG * IMG_H * IMG_W); // 8 KB

    const int n4 = NIMG * IMG_H * IMG_W / 4;   // 4,194,304
    quantize_kernel<<<8192, 256, 0, stream>>>(images, g, n4);
    glcm_kernel<<<NIMG * NOFF, 256, 0, stream>>>(g, feats);
    reduce_kernel<<<1, 256, 0, stream>>>(feats, out);
}

// Round 2
// 98.545 us; speedup vs baseline: 3.5314x; 3.5314x over previous
//
#include <hip/hip_runtime.h>

#define LV 32
#define NBINS (LV*LV)
#define IMG_H 512
#define IMG_W 512
#define NIMG 64
#define NUQ 6
#define NSTRIP 16
#define STRIP_H (IMG_H / NSTRIP)

// 8 reference offsets contain (1,1) and (1,-1) twice -> 6 unique, weighted.
__device__ __constant__ int UOFF_DR[NUQ]  = {0, 1, 1,  1, 0, 2};
__device__ __constant__ int UOFF_DC[NUQ]  = {1, 1, 0, -1, 2, 0};
__device__ __constant__ float UOFF_W[NUQ] = {1.f, 2.f, 1.f, 2.f, 1.f, 1.f};

// ---------------- Kernel 1: quantize (HBM-bound, at roofline) ----------------
__device__ __forceinline__ unsigned char quant1(float x, float y, float z) {
    float gray = (x + y + z) / 3.0f;
    float t = (gray + 1.0f) * 0.5f * 31.0f;
    t = fminf(fmaxf(t, 0.0f), 31.0f);
    return (unsigned char)(int)t;
}

__global__ __launch_bounds__(256) void quantize_kernel(
    const float* __restrict__ in, unsigned char* __restrict__ g, int n4) {
    const int stride = gridDim.x * blockDim.x;
    for (int q = blockIdx.x * blockDim.x + threadIdx.x; q < n4; q += stride) {
        int pix = q << 2;
        int b = pix >> 18;
        int within = pix & (IMG_H * IMG_W - 1);
        const float* base = in + (size_t)b * (3 * IMG_H * IMG_W) + within;
        float4 c0 = *(const float4*)(base);
        float4 c1 = *(const float4*)(base + IMG_H * IMG_W);
        float4 c2 = *(const float4*)(base + 2 * IMG_H * IMG_W);
        uchar4 o;
        o.x = quant1(c0.x, c1.x, c2.x);
        o.y = quant1(c0.y, c1.y, c2.y);
        o.z = quant1(c0.z, c1.z, c2.z);
        o.w = quant1(c0.w, c1.w, c2.w);
        *(uchar4*)(g + pix) = o;
    }
}

// ---------------- Kernel 2: strip histograms ----------------
// grid = NIMG * NUQ * NSTRIP; per-wave LDS sub-histograms, combine to global u32.
__device__ __forceinline__ int hswz(int i, int j) {
    return (i << 5) | ((i + j) & 31);   // bank = (i+j)&31: spreads peaked bins
}

__device__ __forceinline__ void pw(unsigned int iv, unsigned int jv,
                                   unsigned int* __restrict__ h) {
    #pragma unroll
    for (int k = 0; k < 4; ++k) {
        int i = (iv >> (8 * k)) & 0xff;
        int j = (jv >> (8 * k)) & 0xff;
        atomicAdd(&h[hswz(i, j)], 1u);
    }
}

__global__ __launch_bounds__(256) void glcm_hist_kernel(
    const unsigned char* __restrict__ g, unsigned int* __restrict__ hist) {
    const int blk = blockIdx.x;
    const int b = blk / (NUQ * NSTRIP);
    const int rem = blk - b * (NUQ * NSTRIP);
    const int u = rem >> 4;
    const int s = rem & (NSTRIP - 1);

    const int dr = UOFF_DR[u], dc = UOFF_DC[u];
    const int r0 = dr < 0 ? -dr : 0;
    const int r1 = IMG_H - (dr > 0 ? dr : 0);
    const int c0 = dc < 0 ? -dc : 0;
    const int c1 = IMG_W - (dc > 0 ? dc : 0);
    const int rs = max(r0, s * STRIP_H);
    const int re = min(r1, s * STRIP_H + STRIP_H);

    __shared__ unsigned int lh[4][NBINS];   // 16 KB
    const int tid = threadIdx.x;
    const int wid = tid >> 6;

    for (int k = tid; k < 4 * NBINS; k += 256) ((unsigned int*)lh)[k] = 0;
    __syncthreads();

    const unsigned char* gb = g + (size_t)b * (IMG_H * IMG_W);
    unsigned int* h = lh[wid];
    const int nr = re - rs;
    if (nr > 0) {
        const int ngroups = nr * (IMG_W / 16);
        for (int idx = tid; idx < ngroups; idx += 256) {
            int r = rs + (idx >> 5);
            int c = (idx & 31) << 4;
            const unsigned char* rowi = gb + (r << 9);
            const unsigned char* rowj = gb + ((r + dr) << 9);
            if (c >= c0 && c + 16 <= c1) {
                uint4 iw = *(const uint4*)(rowi + c);
                unsigned int jw0, jw1, jw2, jw3;
                if (dc == 0) {
                    uint4 t = *(const uint4*)(rowj + c);
                    jw0 = t.x; jw1 = t.y; jw2 = t.z; jw3 = t.w;
                } else {
                    const unsigned char* jp = rowj + c + dc;
                    int sh = (int)((uintptr_t)jp & 3);
                    const unsigned int* jwp = (const unsigned int*)(jp - sh);
                    unsigned int w0 = jwp[0], w1 = jwp[1], w2 = jwp[2],
                                 w3 = jwp[3], w4 = jwp[4];
                    int sb = sh * 8;          // 8, 16, or 24 (never 0 here)
                    jw0 = (w0 >> sb) | (w1 << (32 - sb));
                    jw1 = (w1 >> sb) | (w2 << (32 - sb));
                    jw2 = (w2 >> sb) | (w3 << (32 - sb));
                    jw3 = (w3 >> sb) | (w4 << (32 - sb));
                }
                pw(iw.x, jw0, h); pw(iw.y, jw1, h);
                pw(iw.z, jw2, h); pw(iw.w, jw3, h);
            } else {
                #pragma unroll 4
                for (int k = 0; k < 16; ++k) {
                    int cc = c + k;
                    if (cc >= c0 && cc < c1) {
                        int i = rowi[cc];
                        int j = rowj[cc + dc];
                        atomicAdd(&h[hswz(i, j)], 1u);
                    }
                }
            }
        }
    }
    __syncthreads();

    unsigned int* hb = hist + ((size_t)(b * NUQ + u) << 10);
    for (int k = tid; k < NBINS; k += 256) {
        unsigned int v = lh[0][k] + lh[1][k] + lh[2][k] + lh[3][k];
        if (v) atomicAdd(&hb[k], v);
    }
}

// ---------------- Kernel 3: features from histograms ----------------
__global__ __launch_bounds__(256) void feature_kernel(
    const unsigned int* __restrict__ hist, float* __restrict__ feats) {
    const int blk = blockIdx.x;            // b*NUQ + u
    const int u = blk % NUQ;
    const int dr = UOFF_DR[u], dc = UOFF_DC[u];
    const int nrow = IMG_H - (dr < 0 ? -dr : dr);
    const int ncol = IMG_W - (dc < 0 ? -dc : dc);
    const float inv_total = 1.0f / (2.0f * (float)(nrow * ncol));

    const unsigned int* hb = hist + ((size_t)blk << 10);
    const int tid = threadIdx.x;
    const int wid = tid >> 6;
    const int lane = tid & 63;

    __shared__ float red[4][6];

    float c_sum = 0.f, h_sum = 0.f, e_sum = 0.f, m1 = 0.f, m2 = 0.f, m12 = 0.f;
    for (int k = tid; k < NBINS; k += 256) {
        int i = k >> 5, j = k & 31;
        float sym = (float)(hb[hswz(i, j)] + hb[hswz(j, i)]);
        float P = sym * inv_total;
        float d = (float)(i - j);
        float d2 = d * d;
        float fi = (float)i, fj = (float)j;
        c_sum += P * d2;
        h_sum += P / (1.0f + d2);
        e_sum += P * P;
        m1  += P * fi;
        m2  += P * fi * fi;
        m12 += P * fi * fj;
    }
    #pragma unroll
    for (int sft = 32; sft > 0; sft >>= 1) {
        c_sum += __shfl_down(c_sum, sft);
        h_sum += __shfl_down(h_sum, sft);
        e_sum += __shfl_down(e_sum, sft);
        m1    += __shfl_down(m1, sft);
        m2    += __shfl_down(m2, sft);
        m12   += __shfl_down(m12, sft);
    }
    if (lane == 0) {
        red[wid][0] = c_sum; red[wid][1] = h_sum; red[wid][2] = e_sum;
        red[wid][3] = m1;    red[wid][4] = m2;    red[wid][5] = m12;
    }
    __syncthreads();
    if (tid == 0) {
        float rc = 0, rh = 0, re2 = 0, rm1 = 0, rm2 = 0, rm12 = 0;
        #pragma unroll
        for (int w = 0; w < 4; ++w) {
            rc += red[w][0]; rh += red[w][1]; re2 += red[w][2];
            rm1 += red[w][3]; rm2 += red[w][4]; rm12 += red[w][5];
        }
        float mu  = rm1;
        float var = rm2 - mu * mu;
        float cov = rm12 - mu * mu;
        float denom = var;                  // std_i * std_j, P symmetric
        float corr = (denom > 1e-15f) ? cov / denom : 1.0f;
        float* f = feats + (size_t)blk * 4;
        f[0] = rc;
        f[1] = rh;
        f[2] = sqrtf(re2);
        f[3] = corr;
    }
}

// ---------------- Kernel 4: weighted average over unique offsets ----------------
__global__ __launch_bounds__(256) void reduce_kernel(
    const float* __restrict__ feats, float* __restrict__ out) {
    int tid = threadIdx.x;                 // 256 = 4 features x 64 images
    int f = tid >> 6, b = tid & 63;
    float s = 0.f;
    #pragma unroll
    for (int u = 0; u < NUQ; ++u) s += UOFF_W[u] * feats[(size_t)(b * NUQ + u) * 4 + f];
    out[f * NIMG + b] = s * 0.125f;
}

extern "C" void kernel_launch(void* const* d_in, const int* in_sizes, int n_in,
                              void* d_out, int out_size, void* d_ws, size_t ws_size,
                              hipStream_t stream) {
    const float* images = (const float*)d_in[0];
    float* out = (float*)d_out;

    unsigned char* g = (unsigned char*)d_ws;                          // 16 MB
    size_t goff = (size_t)NIMG * IMG_H * IMG_W;
    unsigned int* hist = (unsigned int*)((char*)d_ws + goff);         // 64*6*4KB = 1.5 MB
    size_t hbytes = (size_t)NIMG * NUQ * NBINS * sizeof(unsigned int);
    float* feats = (float*)((char*)d_ws + goff + hbytes);             // 6 KB

    hipMemsetAsync(hist, 0, hbytes, stream);

    const int n4 = NIMG * IMG_H * IMG_W / 4;
    quantize_kernel<<<8192, 256, 0, stream>>>(images, g, n4);
    glcm_hist_kernel<<<NIMG * NUQ * NSTRIP, 256, 0, stream>>>(g, hist);
    feature_kernel<<<NIMG * NUQ, 256, 0, stream>>>(hist, feats);
    reduce_kernel<<<1, 256, 0, stream>>>(feats, out);
}

// Round 3
// 89.985 us; speedup vs baseline: 3.8674x; 1.0951x over previous
//
#include <hip/hip_runtime.h>

#define LV 32
#define NBINS (LV*LV)
#define IMG_H 512
#define IMG_W 512
#define NIMG 64
#define NUQ 6
#define NSTRIP 16
#define STRIP_H 32

// 8 reference offsets contain (1,1) and (1,-1) twice -> 6 unique, weighted.
__device__ __constant__ int UOFF_DR[NUQ]  = {0, 1, 1,  1, 0, 2};
__device__ __constant__ int UOFF_DC[NUQ]  = {1, 1, 0, -1, 2, 0};
__device__ __constant__ float UOFF_W[NUQ] = {1.f, 2.f, 1.f, 2.f, 1.f, 1.f};

__device__ __forceinline__ unsigned char quant1(float x, float y, float z) {
    float gray = (x + y + z) / 3.0f;
    float t = (gray + 1.0f) * 0.5f * 31.0f;
    t = fminf(fmaxf(t, 0.0f), 31.0f);
    return (unsigned char)(int)t;
}

// packed-u16 hist: dword d = (i<<4) | ((i + (j>>1)) & 15); half = j&1.
__device__ __forceinline__ void ppair(int i, int j, unsigned int* __restrict__ hu) {
    int d = (i << 4) | ((i + (j >> 1)) & 15);
    atomicAdd(&hu[d], 1u << ((j & 1) << 4));
}

// ---------------- Fused kernel: quantize strip -> LDS tile -> 6 histograms ----------------
__global__ __launch_bounds__(256) void glcm_fused_kernel(
    const float* __restrict__ in, unsigned int* __restrict__ hist_g) {
    const int b = blockIdx.x >> 4;
    const int s = blockIdx.x & 15;
    const int rs = s * STRIP_H;
    const int trows = min(IMG_H - rs, STRIP_H + 2);   // 34 (32 for last strip)

    __shared__ unsigned char tile[(STRIP_H + 2) * IMG_W];   // 17408 B
    __shared__ unsigned int hist[NUQ * 512];                // 12288 B (packed u16 pairs)

    const int tid = threadIdx.x;

    // zero hists
    for (int k = tid; k < NUQ * 512; k += 256) hist[k] = 0;

    // quantize strip (+halo) into tile
    const float* ib = in + (size_t)b * (3 * IMG_H * IMG_W);
    const int nitems = trows << 7;                    // 128 uchar4-groups per row
    for (int idx = tid; idx < nitems; idx += 256) {
        int r = idx >> 7;
        int c4 = (idx & 127) << 2;
        int pix = ((rs + r) << 9) + c4;
        float4 a0 = *(const float4*)(ib + pix);
        float4 a1 = *(const float4*)(ib + IMG_H * IMG_W + pix);
        float4 a2 = *(const float4*)(ib + 2 * IMG_H * IMG_W + pix);
        unsigned int q =
            (unsigned int)quant1(a0.x, a1.x, a2.x)
            | ((unsigned int)quant1(a0.y, a1.y, a2.y) << 8)
            | ((unsigned int)quant1(a0.z, a1.z, a2.z) << 16)
            | ((unsigned int)quant1(a0.w, a1.w, a2.w) << 24);
        *(unsigned int*)&tile[(r << 9) + c4] = q;
    }
    __syncthreads();

    const unsigned int* t32 = (const unsigned int*)tile;
    const uint4* t128 = (const uint4*)tile;

    for (int u = 0; u < NUQ; ++u) {
        const int dr = UOFF_DR[u], dc = UOFF_DC[u];
        const int nr = min(IMG_H - dr, rs + STRIP_H) - rs;   // 32 (less on last strip)
        const int c0 = dc < 0 ? -dc : 0;
        const int c1 = IMG_W - (dc > 0 ? dc : 0);
        const int gA = (c0 + 15) >> 4;
        const int gEnd = c1 >> 4;
        const int ng = gEnd - gA;
        const int m = (ng == 32) ? 2048 : 2115;              // idx/ng via mulhi, idx<1024
        unsigned int* hu = hist + (u << 9);

        const int nint = nr * ng;
        for (int idx = tid; idx < nint; idx += 256) {
            int r = (idx * m) >> 16;
            int g = idx - r * ng + gA;
            uint4 iw = t128[(r << 5) + g];
            unsigned int jw0, jw1, jw2, jw3;
            if (dc == 0) {
                uint4 jv = t128[((r + dr) << 5) + g];
                jw0 = jv.x; jw1 = jv.y; jw2 = jv.z; jw3 = jv.w;
            } else {
                int jb = ((r + dr) << 9) + (g << 4) + dc;    // byte addr, may be unaligned
                int wi = jb >> 2;
                int sb = (jb & 3) << 3;
                unsigned int w0 = t32[wi], w1 = t32[wi + 1], w2 = t32[wi + 2],
                             w3 = t32[wi + 3], w4 = t32[wi + 4];
                jw0 = (w0 >> sb) | (w1 << (32 - sb));
                jw1 = (w1 >> sb) | (w2 << (32 - sb));
                jw2 = (w2 >> sb) | (w3 << (32 - sb));
                jw3 = (w3 >> sb) | (w4 << (32 - sb));
            }
            #pragma unroll
            for (int k = 0; k < 4; ++k) {
                ppair((iw.x >> (8 * k)) & 255, (jw0 >> (8 * k)) & 255, hu);
                ppair((iw.y >> (8 * k)) & 255, (jw1 >> (8 * k)) & 255, hu);
                ppair((iw.z >> (8 * k)) & 255, (jw2 >> (8 * k)) & 255, hu);
                ppair((iw.w >> (8 * k)) & 255, (jw3 >> (8 * k)) & 255, hu);
            }
        }

        // ragged edge columns (<=15 left + <=15 right per row)
        for (int r = tid; r < nr; r += 256) {
            const int ri = r << 9, rj = (r + dr) << 9;
            for (int c = c0; c < (gA << 4); ++c)
                ppair(tile[ri + c], tile[rj + c + dc], hu);
            for (int c = (gEnd << 4); c < c1; ++c)
                ppair(tile[ri + c], tile[rj + c + dc], hu);
        }
    }
    __syncthreads();

    // flush: unpack u16 pairs -> global u32 atomics, plain (i<<5)|j layout
    for (int k = tid; k < NUQ * 512; k += 256) {
        unsigned int v = hist[k];
        if (!v) continue;
        int u = k >> 9;
        int d = k & 511;
        int i = d >> 4;
        int jh = ((d & 15) - i) & 15;
        unsigned int lo = v & 0xffffu, hi = v >> 16;
        unsigned int* hb = hist_g + (((size_t)b * NUQ + u) << 10);
        int base = (i << 5) | (jh << 1);
        if (lo) atomicAdd(&hb[base], lo);
        if (hi) atomicAdd(&hb[base | 1], hi);
    }
}

// ---------------- features from histograms ----------------
__global__ __launch_bounds__(256) void feature_kernel(
    const unsigned int* __restrict__ hist, float* __restrict__ feats) {
    const int blk = blockIdx.x;            // b*NUQ + u
    const int u = blk % NUQ;
    const int dr = UOFF_DR[u], dc = UOFF_DC[u];
    const int nrow = IMG_H - (dr < 0 ? -dr : dr);
    const int ncol = IMG_W - (dc < 0 ? -dc : dc);
    const float inv_total = 1.0f / (2.0f * (float)(nrow * ncol));

    const unsigned int* hb = hist + ((size_t)blk << 10);
    const int tid = threadIdx.x;
    const int wid = tid >> 6;
    const int lane = tid & 63;

    __shared__ float red[4][6];

    float c_sum = 0.f, h_sum = 0.f, e_sum = 0.f, m1 = 0.f, m2 = 0.f, m12 = 0.f;
    for (int k = tid; k < NBINS; k += 256) {
        int i = k >> 5, j = k & 31;
        float sym = (float)(hb[k] + hb[(j << 5) | i]);
        float P = sym * inv_total;
        float d = (float)(i - j);
        float d2 = d * d;
        float fi = (float)i, fj = (float)j;
        c_sum += P * d2;
        h_sum += P / (1.0f + d2);
        e_sum += P * P;
        m1  += P * fi;
        m2  += P * fi * fi;
        m12 += P * fi * fj;
    }
    #pragma unroll
    for (int sft = 32; sft > 0; sft >>= 1) {
        c_sum += __shfl_down(c_sum, sft);
        h_sum += __shfl_down(h_sum, sft);
        e_sum += __shfl_down(e_sum, sft);
        m1    += __shfl_down(m1, sft);
        m2    += __shfl_down(m2, sft);
        m12   += __shfl_down(m12, sft);
    }
    if (lane == 0) {
        red[wid][0] = c_sum; red[wid][1] = h_sum; red[wid][2] = e_sum;
        red[wid][3] = m1;    red[wid][4] = m2;    red[wid][5] = m12;
    }
    __syncthreads();
    if (tid == 0) {
        float rc = 0, rh = 0, re2 = 0, rm1 = 0, rm2 = 0, rm12 = 0;
        #pragma unroll
        for (int w = 0; w < 4; ++w) {
            rc += red[w][0]; rh += red[w][1]; re2 += red[w][2];
            rm1 += red[w][3]; rm2 += red[w][4]; rm12 += red[w][5];
        }
        float mu  = rm1;
        float var = rm2 - mu * mu;
        float cov = rm12 - mu * mu;
        float denom = var;                  // std_i*std_j, P symmetric
        float corr = (denom > 1e-15f) ? cov / denom : 1.0f;
        float* f = feats + (size_t)blk * 4;
        f[0] = rc;
        f[1] = rh;
        f[2] = sqrtf(re2);
        f[3] = corr;
    }
}

// ---------------- weighted average over unique offsets ----------------
__global__ __launch_bounds__(256) void reduce_kernel(
    const float* __restrict__ feats, float* __restrict__ out) {
    int tid = threadIdx.x;                 // 256 = 4 features x 64 images
    int f = tid >> 6, b = tid & 63;
    float s = 0.f;
    #pragma unroll
    for (int u = 0; u < NUQ; ++u) s += UOFF_W[u] * feats[(size_t)(b * NUQ + u) * 4 + f];
    out[f * NIMG + b] = s * 0.125f;
}

extern "C" void kernel_launch(void* const* d_in, const int* in_sizes, int n_in,
                              void* d_out, int out_size, void* d_ws, size_t ws_size,
                              hipStream_t stream) {
    const float* images = (const float*)d_in[0];
    float* out = (float*)d_out;

    unsigned int* hist = (unsigned int*)d_ws;                 // 64*6*4KB = 1.5 MB
    size_t hbytes = (size_t)NIMG * NUQ * NBINS * sizeof(unsigned int);
    float* feats = (float*)((char*)d_ws + hbytes);            // 6 KB

    hipMemsetAsync(hist, 0, hbytes, stream);
    glcm_fused_kernel<<<NIMG * NSTRIP, 256, 0, stream>>>(images, hist);
    feature_kernel<<<NIMG * NUQ, 256, 0, stream>>>(hist, feats);
    reduce_kernel<<<1, 256, 0, stream>>>(feats, out);
}

// Round 4
// 65.276 us; speedup vs baseline: 5.3313x; 1.3785x over previous
//
#include <hip/hip_runtime.h>

#define NIMG 64
#define NUQ 6
#define NSTRIP 16
#define SROWS 32
#define HW (512 * 512)

// 8 reference offsets contain (1,1) and (1,-1) twice -> 6 unique, weighted.
__device__ __constant__ float UOFF_W[NUQ] = {1.f, 2.f, 1.f, 2.f, 1.f, 1.f};
// dr nibbles {0,1,1,1,0,2}; (dc+1) nibbles {2,2,1,0,3,1}
#define DR_PACK 0x201110u
#define DCP_PACK 0x130122u

__device__ __forceinline__ unsigned char quant1(float x, float y, float z) {
    float gray = (x + y + z) / 3.0f;
    float t = (gray + 1.0f) * 0.5f * 31.0f;
    t = fminf(fmaxf(t, 0.0f), 31.0f);
    return (unsigned char)(int)t;
}

// packed-u16 hist: dword d = (i<<4) | ((i + (j>>1)) & 15); half = j&1.
__device__ __forceinline__ void ppair(int i, int j, unsigned int* __restrict__ hu) {
    int d = (i << 4) | ((i + (j >> 1)) & 15);
    atomicAdd(&hu[d], 1u << ((j & 1) << 4));
}

// ---- Fused: per (image, 32-row strip); ring-buffered quantize || histogram ----
__global__ __launch_bounds__(256) void glcm_fused(
    const float* __restrict__ in, unsigned int* __restrict__ hist_g) {
    const int b = blockIdx.x >> 4;
    const int s = blockIdx.x & 15;
    const int rs = s * SROWS;

    __shared__ unsigned char ring[4 * 2048];   // 4 chunk slots x (4 rows x 512)
    __shared__ unsigned int hist[NUQ * 512];   // packed u16-pair bins, 12 KB

    const int tid = threadIdx.x;
    for (int k = tid; k < NUQ * 512; k += 256) hist[k] = 0;

    const float* ib = in + (size_t)b * (3 * HW);
    const int lrow = tid >> 6;            // row within chunk
    const int lcol = (tid & 63) << 3;     // 8 pixels per thread

    float4 A0, B0, A1, B1, A2, B2;

    for (int c = 0; c <= 9; ++c) {
        // ---- (1) issue loads for chunk c (use is deferred past hist) ----
        const int gr = rs + (c << 2) + lrow;
        const bool doload = (c <= 8) && ((c << 2) + lrow < SROWS + 2) && (gr < 512);
        if (doload) {
            const float* p = ib + ((size_t)gr << 9) + lcol;
            A0 = *(const float4*)(p);
            B0 = *(const float4*)(p + 4);
            A1 = *(const float4*)(p + HW);
            B1 = *(const float4*)(p + HW + 4);
            A2 = *(const float4*)(p + 2 * HW);
            B2 = *(const float4*)(p + 2 * HW + 4);
        }

        // ---- (2) histogram chunk c-2 (rows 4(c-2)..4(c-2)+3 of strip) ----
        if (c >= 2) {
            const int k = c - 2;
            // main: 6 offsets x 4 rows x 32 full 16-px groups = 768 slots
            for (int idx = tid; idx < 768; idx += 256) {
                int u = idx >> 7;                       // wave-uniform
                int rem = idx & 127;
                int r4 = rem >> 5;
                int g = rem & 31;
                int dr = (DR_PACK >> (u << 2)) & 15;
                int dc = (int)((DCP_PACK >> (u << 2)) & 15) - 1;
                int R = (k << 2) + r4;
                int nr_u = min(512 - dr - rs, SROWS);
                int gA = (dc < 0) ? 1 : 0;
                int gEnd = (dc > 0) ? 31 : 32;
                if (R < nr_u && g >= gA && g < gEnd) {
                    const uint4* ip = (const uint4*)(ring + ((k & 3) << 11) + (r4 << 9) + (g << 4));
                    uint4 iw = *ip;
                    int Rj = R + dr;
                    int jbase = (((Rj >> 2) & 3) << 11) + ((Rj & 3) << 9);
                    unsigned int jw0, jw1, jw2, jw3;
                    if (dc == 0) {
                        uint4 jv = *(const uint4*)(ring + jbase + (g << 4));
                        jw0 = jv.x; jw1 = jv.y; jw2 = jv.z; jw3 = jv.w;
                    } else {
                        int jb = jbase + (g << 4) + dc;
                        const unsigned int* t32 = (const unsigned int*)(ring + (jb & ~3));
                        int sb = (jb & 3) << 3;          // 8, 16 or 24 (never 0)
                        unsigned int w0 = t32[0], w1 = t32[1], w2 = t32[2],
                                     w3 = t32[3], w4 = t32[4];
                        jw0 = (w0 >> sb) | (w1 << (32 - sb));
                        jw1 = (w1 >> sb) | (w2 << (32 - sb));
                        jw2 = (w2 >> sb) | (w3 << (32 - sb));
                        jw3 = (w3 >> sb) | (w4 << (32 - sb));
                    }
                    unsigned int* hu = hist + (u << 9);
                    #pragma unroll
                    for (int q = 0; q < 4; ++q) {
                        ppair((iw.x >> (8 * q)) & 255, (jw0 >> (8 * q)) & 255, hu);
                        ppair((iw.y >> (8 * q)) & 255, (jw1 >> (8 * q)) & 255, hu);
                        ppair((iw.z >> (8 * q)) & 255, (jw2 >> (8 * q)) & 255, hu);
                        ppair((iw.w >> (8 * q)) & 255, (jw3 >> (8 * q)) & 255, hu);
                    }
                }
            }
            // edges: 6 offsets x 4 rows x <=15 ragged cols = 384 slots
            for (int idx = tid; idx < 384; idx += 256) {
                int u = idx >> 6;                       // wave-uniform
                int rem = idx & 63;
                int r4 = rem >> 4;
                int e = rem & 15;
                int dr = (DR_PACK >> (u << 2)) & 15;
                int dc = (int)((DCP_PACK >> (u << 2)) & 15) - 1;
                int elen = (dc == 0) ? 0 : ((dc == 2) ? 14 : 15);
                int ebase = (dc < 0) ? 1 : 496;
                int R = (k << 2) + r4;
                int nr_u = min(512 - dr - rs, SROWS);
                if (e < elen && R < nr_u) {
                    int ci = ebase + e;
                    int ia = ((k & 3) << 11) + (r4 << 9) + ci;
                    int Rj = R + dr;
                    int ja = (((Rj >> 2) & 3) << 11) + ((Rj & 3) << 9) + ci + dc;
                    ppair(ring[ia], ring[ja], hist + (u << 9));
                }
            }
        }

        // ---- (3) quantize chunk c into ring slot c&3 ----
        if (doload) {
            unsigned int q0 =
                (unsigned int)quant1(A0.x, A1.x, A2.x)
                | ((unsigned int)quant1(A0.y, A1.y, A2.y) << 8)
                | ((unsigned int)quant1(A0.z, A1.z, A2.z) << 16)
                | ((unsigned int)quant1(A0.w, A1.w, A2.w) << 24);
            unsigned int q1 =
                (unsigned int)quant1(B0.x, B1.x, B2.x)
                | ((unsigned int)quant1(B0.y, B1.y, B2.y) << 8)
                | ((unsigned int)quant1(B0.z, B1.z, B2.z) << 16)
                | ((unsigned int)quant1(B0.w, B1.w, B2.w) << 24);
            uint2* wp = (uint2*)(ring + ((c & 3) << 11) + (lrow << 9) + lcol);
            *wp = make_uint2(q0, q1);
        }
        __syncthreads();
    }

    // ---- flush packed strip-hist with plain stores (no memset, no atomics) ----
    unsigned int* hb = hist_g + (size_t)blockIdx.x * (NUQ * 512);
    for (int k = tid; k < NUQ * 512; k += 256) hb[k] = hist[k];
}

// ---- features: sum 16 strips, unpack, moments ----
__global__ __launch_bounds__(256) void feature_kernel(
    const unsigned int* __restrict__ hist_g, float* __restrict__ feats) {
    const int blk = blockIdx.x;            // b*NUQ + u
    const int b = blk / NUQ;
    const int u = blk - b * NUQ;
    const int dr = (DR_PACK >> (u << 2)) & 15;
    const int dc = (int)((DCP_PACK >> (u << 2)) & 15) - 1;
    const int adc = dc < 0 ? -dc : dc;
    const float inv_total = 1.0f / (2.0f * (float)((512 - dr) * (512 - adc)));

    __shared__ unsigned int cnt[1024];
    __shared__ float red[4][6];
    const int tid = threadIdx.x;
    const int wid = tid >> 6;
    const int lane = tid & 63;

    for (int d = tid; d < 512; d += 256) {
        unsigned int lo = 0, hi = 0;
        const unsigned int* p = hist_g + ((size_t)(b * NSTRIP) * NUQ + u) * 512 + d;
        #pragma unroll
        for (int st = 0; st < NSTRIP; ++st) {
            unsigned int v = p[(size_t)st * NUQ * 512];
            lo += v & 0xffffu;
            hi += v >> 16;
        }
        int i = d >> 4;
        int jh = ((d & 15) - i) & 15;
        cnt[(i << 5) | (jh << 1)] = lo;
        cnt[(i << 5) | (jh << 1) | 1] = hi;
    }
    __syncthreads();

    float c_sum = 0.f, h_sum = 0.f, e_sum = 0.f, m1 = 0.f, m2 = 0.f, m12 = 0.f;
    for (int k = tid; k < 1024; k += 256) {
        int i = k >> 5, j = k & 31;
        float sym = (float)(cnt[k] + cnt[(j << 5) | i]);
        float P = sym * inv_total;
        float d = (float)(i - j);
        float d2 = d * d;
        float fi = (float)i, fj = (float)j;
        c_sum += P * d2;
        h_sum += P / (1.0f + d2);
        e_sum += P * P;
        m1  += P * fi;
        m2  += P * fi * fi;
        m12 += P * fi * fj;
    }
    #pragma unroll
    for (int sft = 32; sft > 0; sft >>= 1) {
        c_sum += __shfl_down(c_sum, sft);
        h_sum += __shfl_down(h_sum, sft);
        e_sum += __shfl_down(e_sum, sft);
        m1    += __shfl_down(m1, sft);
        m2    += __shfl_down(m2, sft);
        m12   += __shfl_down(m12, sft);
    }
    if (lane == 0) {
        red[wid][0] = c_sum; red[wid][1] = h_sum; red[wid][2] = e_sum;
        red[wid][3] = m1;    red[wid][4] = m2;    red[wid][5] = m12;
    }
    __syncthreads();
    if (tid == 0) {
        float rc = 0, rh = 0, re2 = 0, rm1 = 0, rm2 = 0, rm12 = 0;
        #pragma unroll
        for (int w = 0; w < 4; ++w) {
            rc += red[w][0]; rh += red[w][1]; re2 += red[w][2];
            rm1 += red[w][3]; rm2 += red[w][4]; rm12 += red[w][5];
        }
        float mu  = rm1;
        float var = rm2 - mu * mu;
        float cov = rm12 - mu * mu;
        float denom = var;                  // std_i*std_j, P symmetric
        float corr = (denom > 1e-15f) ? cov / denom : 1.0f;
        float* f = feats + (size_t)blk * 4;
        f[0] = rc;
        f[1] = rh;
        f[2] = sqrtf(re2);
        f[3] = corr;
    }
}

// ---- weighted average over unique offsets ----
__global__ __launch_bounds__(256) void reduce_kernel(
    const float* __restrict__ feats, float* __restrict__ out) {
    int tid = threadIdx.x;                 // 256 = 4 features x 64 images
    int f = tid >> 6, b = tid & 63;
    float s = 0.f;
    #pragma unroll
    for (int u = 0; u < NUQ; ++u) s += UOFF_W[u] * feats[(size_t)(b * NUQ + u) * 4 + f];
    out[f * NIMG + b] = s * 0.125f;
}

extern "C" void kernel_launch(void* const* d_in, const int* in_sizes, int n_in,
                              void* d_out, int out_size, void* d_ws, size_t ws_size,
                              hipStream_t stream) {
    const float* images = (const float*)d_in[0];
    float* out = (float*)d_out;

    unsigned int* hist_g = (unsigned int*)d_ws;   // 1024 blocks x 3072 u32 = 12.6 MB
    size_t hbytes = (size_t)NIMG * NSTRIP * NUQ * 512 * sizeof(unsigned int);
    float* feats = (float*)((char*)d_ws + hbytes);

    glcm_fused<<<NIMG * NSTRIP, 256, 0, stream>>>(images, hist_g);
    feature_kernel<<<NIMG * NUQ, 256, 0, stream>>>(hist_g, feats);
    reduce_kernel<<<1, 256, 0, stream>>>(feats, out);
}